// Round 5
// baseline (1374.457 us; speedup 1.0000x reference)
//
#include <hip/hip_runtime.h>

#define F_IN 256
#define EDIM 128
#define ALPHA 0.2f
#define SCAN_B 1024
#define BM 128
#define BK 16
#define BROWS 128   // rows per bucket (local-sort tile); needs n < 2^17 for packing

typedef unsigned short u16;
typedef unsigned int u32;

__device__ __forceinline__ float b2f(u16 b) {
    union { u32 u; float f; } v; v.u = ((u32)b) << 16; return v.f;
}
__device__ __forceinline__ u16 f2b(float f) {
    union { float f; u32 u; } v; v.f = f;
    u32 r = v.u + 0x7FFFu + ((v.u >> 16) & 1u);
    return (u16)(r >> 16);
}
__device__ __forceinline__ float unpack_lo(u32 g) {
    union { u32 u; float f; } v; v.u = g << 16; return v.f;
}
__device__ __forceinline__ float unpack_hi(u32 g) {
    union { u32 u; float f; } v; v.u = g & 0xFFFF0000u; return v.f;
}

// ---------------- CSR build ----------------

__global__ void k_hist(const int* __restrict__ erow, int* __restrict__ cnt, int nE) {
    int e = blockIdx.x * 256 + threadIdx.x;
    if (e < nE) atomicAdd(&cnt[erow[e]], 1);
}

__global__ void k_scan_block(const int* __restrict__ cnt, int* __restrict__ rp,
                             int* __restrict__ bsum, int n) {
    __shared__ int s[SCAN_B];
    int t = threadIdx.x;
    int i = blockIdx.x * SCAN_B + t;
    int v = (i < n) ? cnt[i] : 0;
    s[t] = v;
    __syncthreads();
    for (int d = 1; d < SCAN_B; d <<= 1) {
        int add = (t >= d) ? s[t - d] : 0;
        __syncthreads();
        s[t] += add;
        __syncthreads();
    }
    if (i < n) rp[i] = s[t] - v;
    if (t == SCAN_B - 1) bsum[blockIdx.x] = s[t];
}

__global__ void k_scan_bsums(const int* __restrict__ bsum, int* __restrict__ boff, int nb) {
    __shared__ int s[SCAN_B];
    int t = threadIdx.x;
    int v = (t < nb) ? bsum[t] : 0;
    s[t] = v;
    __syncthreads();
    for (int d = 1; d < SCAN_B; d <<= 1) {
        int add = (t >= d) ? s[t - d] : 0;
        __syncthreads();
        s[t] += add;
        __syncthreads();
    }
    if (t < nb) boff[t] = s[t] - v;
    if (t == SCAN_B - 1) boff[nb] = s[t];
}

__global__ void k_add_off(int* __restrict__ rp, const int* __restrict__ boff, int n, int nb) {
    int i = blockIdx.x * SCAN_B + threadIdx.x;
    if (i < n) rp[i] += boff[blockIdx.x];
    if (i == n) rp[n] = boff[nb];
}

// bucket write cursors = rowptr at bucket starts
__global__ void k_bucket_init(const int* __restrict__ rowptr, int* __restrict__ bcur,
                              int nbk, int n) {
    int b = blockIdx.x * 256 + threadIdx.x;
    if (b < nbk) bcur[b] = rowptr[min(b * BROWS, n)];
}

// Pass A: scatter edges into their bucket's contiguous region (order arbitrary).
// Packs local row (7b) above the 17b col; val carried as f32 bits.
__global__ void k_scatter_bucket(const int* __restrict__ erow, const int* __restrict__ ecol,
                                 const float* __restrict__ eval, int* __restrict__ bcur,
                                 int2* __restrict__ ebuf, int nE) {
    int e = blockIdx.x * 256 + threadIdx.x;
    if (e >= nE) return;
    int r = erow[e];
    int pos = atomicAdd(&bcur[r >> 7], 1);
    ebuf[pos] = make_int2(ecol[e] | ((r & (BROWS - 1)) << 17), __float_as_int(eval[e]));
}

// Pass B: one WG per bucket; LDS counters give exact CSR slots; writes stay
// inside the bucket's ~32KB window (L2-resident, full-dirty lines).
__global__ __launch_bounds__(256) void k_local_sort(const int* __restrict__ rowptr,
                                                    const int2* __restrict__ ebuf,
                                                    int2* __restrict__ edges, int n) {
    __shared__ int cur[BROWS];
    const int b = blockIdx.x;
    const int r0 = b * BROWS;
    const int t = threadIdx.x;
    const int rend = min(r0 + BROWS, n);
    if (t < BROWS && r0 + t < n) cur[t] = rowptr[r0 + t];
    __syncthreads();
    const int beg = rowptr[r0];
    const int end = rowptr[rend];
    for (int j = beg + t; j < end; j += 256) {
        int2 e = ebuf[j];
        int lrow = (e.x >> 17) & (BROWS - 1);
        int pos = atomicAdd(&cur[lrow], 1);
        edges[pos] = make_int2(e.x & 0x1FFFF, e.y);
    }
}

// ---------------- dense ----------------

__global__ void k_transpose_catW(const float* __restrict__ catW, float* __restrict__ Wt) {
    int idx = blockIdx.x * 256 + threadIdx.x;
    if (idx < EDIM * 2 * EDIM) {
        int r = idx >> 8;
        int c = idx & 255;
        Wt[c * EDIM + r] = catW[idx];
    }
}

#define FMA_ROW(accv, a, bv) \
    accv.x = fmaf(a, bv.x, accv.x); accv.y = fmaf(a, bv.y, accv.y); \
    accv.z = fmaf(a, bv.z, accv.z); accv.w = fmaf(a, bv.w, accv.w);

__global__ __launch_bounds__(256) void k_gemm1_relu(const float* __restrict__ feature,
                                                    const float* __restrict__ W,
                                                    u16* __restrict__ supb, int n) {
    __shared__ float As[BK][BM + 4];
    __shared__ float Bs[BK][EDIM];
    const int t = threadIdx.x;
    const int tr = t >> 4, tc = t & 15;
    const int r0 = blockIdx.x * BM;
    float4 acc[2][4][2];
    #pragma unroll
    for (int rh = 0; rh < 2; ++rh)
        #pragma unroll
        for (int i = 0; i < 4; ++i)
            #pragma unroll
            for (int ch = 0; ch < 2; ++ch)
                acc[rh][i][ch] = make_float4(0.f, 0.f, 0.f, 0.f);

    for (int kt = 0; kt < F_IN / BK; ++kt) {
        const int k0 = kt * BK;
        #pragma unroll
        for (int i = 0; i < 2; ++i) {
            int u = t * 2 + i;
            int r = u >> 2;
            int kc = (u & 3) * 4;
            float4 v = make_float4(0.f, 0.f, 0.f, 0.f);
            if (r0 + r < n)
                v = *reinterpret_cast<const float4*>(feature + (size_t)(r0 + r) * F_IN + k0 + kc);
            As[kc + 0][r] = v.x; As[kc + 1][r] = v.y;
            As[kc + 2][r] = v.z; As[kc + 3][r] = v.w;
        }
        #pragma unroll
        for (int i = 0; i < 2; ++i) {
            int u = t * 2 + i;
            int kb = u >> 5;
            int cb = (u & 31) * 4;
            *reinterpret_cast<float4*>(&Bs[kb][cb]) =
                *reinterpret_cast<const float4*>(W + (size_t)(k0 + kb) * EDIM + cb);
        }
        __syncthreads();
        #pragma unroll
        for (int k = 0; k < BK; ++k) {
            float4 a0 = *reinterpret_cast<const float4*>(&As[k][tr * 4]);
            float4 a1 = *reinterpret_cast<const float4*>(&As[k][64 + tr * 4]);
            float4 b0 = *reinterpret_cast<const float4*>(&Bs[k][tc * 4]);
            float4 b1 = *reinterpret_cast<const float4*>(&Bs[k][64 + tc * 4]);
            FMA_ROW(acc[0][0][0], a0.x, b0) FMA_ROW(acc[0][0][1], a0.x, b1)
            FMA_ROW(acc[0][1][0], a0.y, b0) FMA_ROW(acc[0][1][1], a0.y, b1)
            FMA_ROW(acc[0][2][0], a0.z, b0) FMA_ROW(acc[0][2][1], a0.z, b1)
            FMA_ROW(acc[0][3][0], a0.w, b0) FMA_ROW(acc[0][3][1], a0.w, b1)
            FMA_ROW(acc[1][0][0], a1.x, b0) FMA_ROW(acc[1][0][1], a1.x, b1)
            FMA_ROW(acc[1][1][0], a1.y, b0) FMA_ROW(acc[1][1][1], a1.y, b1)
            FMA_ROW(acc[1][2][0], a1.z, b0) FMA_ROW(acc[1][2][1], a1.z, b1)
            FMA_ROW(acc[1][3][0], a1.w, b0) FMA_ROW(acc[1][3][1], a1.w, b1)
        }
        __syncthreads();
    }
    #pragma unroll
    for (int rh = 0; rh < 2; ++rh)
        #pragma unroll
        for (int i = 0; i < 4; ++i) {
            int row = r0 + rh * 64 + tr * 4 + i;
            if (row >= n) continue;
            u16* dst = supb + (size_t)row * EDIM;
            float4 v0 = acc[rh][i][0], v1 = acc[rh][i][1];
            ushort4 o0, o1;
            o0.x = f2b(fmaxf(v0.x, 0.f)); o0.y = f2b(fmaxf(v0.y, 0.f));
            o0.z = f2b(fmaxf(v0.z, 0.f)); o0.w = f2b(fmaxf(v0.w, 0.f));
            o1.x = f2b(fmaxf(v1.x, 0.f)); o1.y = f2b(fmaxf(v1.y, 0.f));
            o1.z = f2b(fmaxf(v1.z, 0.f)); o1.w = f2b(fmaxf(v1.w, 0.f));
            *reinterpret_cast<ushort4*>(dst + tc * 4) = o0;
            *reinterpret_cast<ushort4*>(dst + 64 + tc * 4) = o1;
        }
}

// y(bf16) = A @ x(bf16): one wave per dest row, lane = 2 cols, f32 accum.
__global__ void k_spmm_csr(const int* __restrict__ rowptr, const int2* __restrict__ edges,
                           const u16* __restrict__ xb, u16* __restrict__ yb, int n) {
    int wid = threadIdx.x >> 6;
    int lane = threadIdx.x & 63;
    int row = blockIdx.x * 4 + wid;
    if (row >= n) return;
    int beg = rowptr[row];
    int end = rowptr[row + 1];
    int c = lane * 2;
    float ax = 0.f, ay = 0.f;
    int j = beg;
    for (; j + 4 <= end; j += 4) {
        int2 e0 = edges[j];
        int2 e1 = edges[j + 1];
        int2 e2 = edges[j + 2];
        int2 e3 = edges[j + 3];
        u32 g0 = *reinterpret_cast<const u32*>(xb + (size_t)e0.x * EDIM + c);
        u32 g1 = *reinterpret_cast<const u32*>(xb + (size_t)e1.x * EDIM + c);
        u32 g2 = *reinterpret_cast<const u32*>(xb + (size_t)e2.x * EDIM + c);
        u32 g3 = *reinterpret_cast<const u32*>(xb + (size_t)e3.x * EDIM + c);
        float v0 = __int_as_float(e0.y), v1 = __int_as_float(e1.y);
        float v2 = __int_as_float(e2.y), v3 = __int_as_float(e3.y);
        ax = fmaf(v0, unpack_lo(g0), ax); ay = fmaf(v0, unpack_hi(g0), ay);
        ax = fmaf(v1, unpack_lo(g1), ax); ay = fmaf(v1, unpack_hi(g1), ay);
        ax = fmaf(v2, unpack_lo(g2), ax); ay = fmaf(v2, unpack_hi(g2), ay);
        ax = fmaf(v3, unpack_lo(g3), ax); ay = fmaf(v3, unpack_hi(g3), ay);
    }
    for (; j < end; ++j) {
        int2 e = edges[j];
        u32 g = *reinterpret_cast<const u32*>(xb + (size_t)e.x * EDIM + c);
        float v = __int_as_float(e.y);
        ax = fmaf(v, unpack_lo(g), ax);
        ay = fmaf(v, unpack_hi(g), ay);
    }
    *reinterpret_cast<u32*>(yb + (size_t)row * EDIM + c) =
        ((u32)f2b(ay) << 16) | (u32)f2b(ax);
}

// out = leaky_relu([s1+sup | s2-sup] @ Wt + catb) + b  (bf16 inputs, f32 out)
__global__ __launch_bounds__(256) void k_final(const u16* __restrict__ supb,
                                               const u16* __restrict__ s1b,
                                               const u16* __restrict__ s2b,
                                               float* __restrict__ out,
                                               const float* __restrict__ Wt,
                                               const float* __restrict__ catb,
                                               const float* __restrict__ bvec, int n) {
    __shared__ float As[BK][BM + 4];
    __shared__ float Bs[BK][EDIM];
    const int t = threadIdx.x;
    const int tr = t >> 4, tc = t & 15;
    const int r0 = blockIdx.x * BM;
    float4 acc[2][4][2];
    #pragma unroll
    for (int rh = 0; rh < 2; ++rh)
        #pragma unroll
        for (int i = 0; i < 4; ++i)
            #pragma unroll
            for (int ch = 0; ch < 2; ++ch)
                acc[rh][i][ch] = make_float4(0.f, 0.f, 0.f, 0.f);

    for (int kt = 0; kt < (2 * EDIM) / BK; ++kt) {
        const int k0 = kt * BK;
        #pragma unroll
        for (int i = 0; i < 2; ++i) {
            int u = t * 2 + i;
            int r = u >> 2;
            int kc = (u & 3) * 4;
            int kk = k0 + kc;
            float4 v = make_float4(0.f, 0.f, 0.f, 0.f);
            if (r0 + r < n) {
                if (kk < EDIM) {
                    size_t off = (size_t)(r0 + r) * EDIM + kk;
                    ushort4 p = *reinterpret_cast<const ushort4*>(s1b + off);
                    ushort4 q = *reinterpret_cast<const ushort4*>(supb + off);
                    v = make_float4(b2f(p.x) + b2f(q.x), b2f(p.y) + b2f(q.y),
                                    b2f(p.z) + b2f(q.z), b2f(p.w) + b2f(q.w));
                } else {
                    size_t off = (size_t)(r0 + r) * EDIM + (kk - EDIM);
                    ushort4 p = *reinterpret_cast<const ushort4*>(s2b + off);
                    ushort4 q = *reinterpret_cast<const ushort4*>(supb + off);
                    v = make_float4(b2f(p.x) - b2f(q.x), b2f(p.y) - b2f(q.y),
                                    b2f(p.z) - b2f(q.z), b2f(p.w) - b2f(q.w));
                }
            }
            As[kc + 0][r] = v.x; As[kc + 1][r] = v.y;
            As[kc + 2][r] = v.z; As[kc + 3][r] = v.w;
        }
        #pragma unroll
        for (int i = 0; i < 2; ++i) {
            int u = t * 2 + i;
            int kb = u >> 5;
            int cb = (u & 31) * 4;
            *reinterpret_cast<float4*>(&Bs[kb][cb]) =
                *reinterpret_cast<const float4*>(Wt + (size_t)(k0 + kb) * EDIM + cb);
        }
        __syncthreads();
        #pragma unroll
        for (int k = 0; k < BK; ++k) {
            float4 a0 = *reinterpret_cast<const float4*>(&As[k][tr * 4]);
            float4 a1 = *reinterpret_cast<const float4*>(&As[k][64 + tr * 4]);
            float4 b0 = *reinterpret_cast<const float4*>(&Bs[k][tc * 4]);
            float4 b1 = *reinterpret_cast<const float4*>(&Bs[k][64 + tc * 4]);
            FMA_ROW(acc[0][0][0], a0.x, b0) FMA_ROW(acc[0][0][1], a0.x, b1)
            FMA_ROW(acc[0][1][0], a0.y, b0) FMA_ROW(acc[0][1][1], a0.y, b1)
            FMA_ROW(acc[0][2][0], a0.z, b0) FMA_ROW(acc[0][2][1], a0.z, b1)
            FMA_ROW(acc[0][3][0], a0.w, b0) FMA_ROW(acc[0][3][1], a0.w, b1)
            FMA_ROW(acc[1][0][0], a1.x, b0) FMA_ROW(acc[1][0][1], a1.x, b1)
            FMA_ROW(acc[1][1][0], a1.y, b0) FMA_ROW(acc[1][1][1], a1.y, b1)
            FMA_ROW(acc[1][2][0], a1.z, b0) FMA_ROW(acc[1][2][1], a1.z, b1)
            FMA_ROW(acc[1][3][0], a1.w, b0) FMA_ROW(acc[1][3][1], a1.w, b1)
        }
        __syncthreads();
    }
    const float4 cb0 = *reinterpret_cast<const float4*>(catb + tc * 4);
    const float4 cb1 = *reinterpret_cast<const float4*>(catb + 64 + tc * 4);
    const float4 bb0 = *reinterpret_cast<const float4*>(bvec + tc * 4);
    const float4 bb1 = *reinterpret_cast<const float4*>(bvec + 64 + tc * 4);
    #pragma unroll
    for (int rh = 0; rh < 2; ++rh)
        #pragma unroll
        for (int i = 0; i < 4; ++i) {
            int row = r0 + rh * 64 + tr * 4 + i;
            if (row >= n) continue;
            float4 v0 = acc[rh][i][0], v1 = acc[rh][i][1];
            v0.x += cb0.x; v0.y += cb0.y; v0.z += cb0.z; v0.w += cb0.w;
            v1.x += cb1.x; v1.y += cb1.y; v1.z += cb1.z; v1.w += cb1.w;
            float4 r4;
            r4.x = (v0.x > 0.f ? v0.x : ALPHA * v0.x) + bb0.x;
            r4.y = (v0.y > 0.f ? v0.y : ALPHA * v0.y) + bb0.y;
            r4.z = (v0.z > 0.f ? v0.z : ALPHA * v0.z) + bb0.z;
            r4.w = (v0.w > 0.f ? v0.w : ALPHA * v0.w) + bb0.w;
            float4 r5;
            r5.x = (v1.x > 0.f ? v1.x : ALPHA * v1.x) + bb1.x;
            r5.y = (v1.y > 0.f ? v1.y : ALPHA * v1.y) + bb1.y;
            r5.z = (v1.z > 0.f ? v1.z : ALPHA * v1.z) + bb1.z;
            r5.w = (v1.w > 0.f ? v1.w : ALPHA * v1.w) + bb1.w;
            float* dst = out + (size_t)row * EDIM;
            *reinterpret_cast<float4*>(dst + tc * 4) = r4;
            *reinterpret_cast<float4*>(dst + 64 + tc * 4) = r5;
        }
}

extern "C" void kernel_launch(void* const* d_in, const int* in_sizes, int n_in,
                              void* d_out, int out_size, void* d_ws, size_t ws_size,
                              hipStream_t stream) {
    const float* feature = (const float*)d_in[0];
    const int*   erow    = (const int*)d_in[1];
    const int*   ecol    = (const int*)d_in[2];
    const float* eval    = (const float*)d_in[3];
    const float* W       = (const float*)d_in[4];
    const float* b       = (const float*)d_in[5];
    const float* catW    = (const float*)d_in[6];
    const float* catb    = (const float*)d_in[7];
    float* out = (float*)d_out;

    const int n  = in_sizes[0] / F_IN;
    const int nE = in_sizes[1];
    const int nb = (n + SCAN_B - 1) / SCAN_B;
    const int nbk = (n + BROWS - 1) / BROWS;

    char* p = (char*)d_ws;
    u16*  supb = (u16*)p;                   p += (size_t)n * EDIM * sizeof(u16);
    u16*  s1b  = (u16*)p;                   p += (size_t)n * EDIM * sizeof(u16);
    u16*  s2b  = (u16*)p;                   p += (size_t)n * EDIM * sizeof(u16);
    p = (char*)(((size_t)p + 15) & ~(size_t)15);
    float* Wt  = (float*)p;                 p += (size_t)F_IN * EDIM * sizeof(float);
    int2* edges = (int2*)p;                 p += (size_t)nE * sizeof(int2);
    int2* ebuf  = (int2*)p;                 p += (size_t)nE * sizeof(int2);
    int*  cnt   = (int*)p;                  p += (size_t)n * sizeof(int);
    int*  rowptr = (int*)p;                 p += (size_t)(n + 1) * sizeof(int);
    int*  bcur   = (int*)p;                 p += (size_t)nbk * sizeof(int);
    int*  bsum   = (int*)p;                 p += (size_t)nb * sizeof(int);
    int*  boff   = (int*)p;                 p += (size_t)(nb + 1) * sizeof(int);

    const int eB = (nE + 255) / 256;
    const int gemmBlocks = (n + BM - 1) / BM;
    const int spmmBlocks = (n + 3) / 4;

    // ---- CSR build (two-level counting sort) ----
    hipMemsetAsync(cnt, 0, (size_t)n * sizeof(int), stream);
    k_hist<<<eB, 256, 0, stream>>>(erow, cnt, nE);
    k_scan_block<<<nb, SCAN_B, 0, stream>>>(cnt, rowptr, bsum, n);
    k_scan_bsums<<<1, SCAN_B, 0, stream>>>(bsum, boff, nb);
    k_add_off<<<nb, SCAN_B, 0, stream>>>(rowptr, boff, n, nb);
    k_bucket_init<<<(nbk + 255) / 256, 256, 0, stream>>>(rowptr, bcur, nbk, n);
    k_scatter_bucket<<<eB, 256, 0, stream>>>(erow, ecol, eval, bcur, ebuf, nE);
    k_local_sort<<<nbk, 256, 0, stream>>>(rowptr, ebuf, edges, n);

    // ---- dense prologue ----
    k_transpose_catW<<<(EDIM * 2 * EDIM + 255) / 256, 256, 0, stream>>>(catW, Wt);
    k_gemm1_relu<<<gemmBlocks, 256, 0, stream>>>(feature, W, supb, n);

    // ---- SpMMs (bf16 gather, f32 accum) ----
    k_spmm_csr<<<spmmBlocks, 256, 0, stream>>>(rowptr, edges, supb, s1b, n);
    k_spmm_csr<<<spmmBlocks, 256, 0, stream>>>(rowptr, edges, s1b, s2b, n);

    // ---- epilogue GEMM ----
    k_final<<<gemmBlocks, 256, 0, stream>>>(supb, s1b, s2b, out, Wt, catb, b, n);
}

// Round 6
// 609.968 us; speedup vs baseline: 2.2533x; 2.2533x over previous
//
#include <hip/hip_runtime.h>

#define F_IN 256
#define EDIM 128
#define ALPHA 0.2f
#define SCAN_B 1024
#define BM 128

typedef unsigned short u16;
typedef unsigned int u32;
typedef __bf16 bf16x8 __attribute__((ext_vector_type(8)));
typedef float f32x4 __attribute__((ext_vector_type(4)));

__device__ __forceinline__ float b2f(u16 b) {
    union { u32 u; float f; } v; v.u = ((u32)b) << 16; return v.f;
}
__device__ __forceinline__ u16 f2b(float f) {
    union { float f; u32 u; } v; v.f = f;
    u32 r = v.u + 0x7FFFu + ((v.u >> 16) & 1u);
    return (u16)(r >> 16);
}
__device__ __forceinline__ float unpack_lo(u32 g) {
    union { u32 u; float f; } v; v.u = g << 16; return v.f;
}
__device__ __forceinline__ float unpack_hi(u32 g) {
    union { u32 u; float f; } v; v.u = g & 0xFFFF0000u; return v.f;
}
__device__ __forceinline__ u32 pack2(float lo, float hi) {
    return ((u32)f2b(hi) << 16) | (u32)f2b(lo);
}

// ---------------- CSR build ----------------

__global__ void k_hist(const int* __restrict__ erow, int* __restrict__ cnt, int nE) {
    int e = blockIdx.x * 256 + threadIdx.x;
    if (e < nE) atomicAdd(&cnt[erow[e]], 1);
}

__global__ void k_scan_block(const int* __restrict__ cnt, int* __restrict__ rp,
                             int* __restrict__ bsum, int n) {
    __shared__ int s[SCAN_B];
    int t = threadIdx.x;
    int i = blockIdx.x * SCAN_B + t;
    int v = (i < n) ? cnt[i] : 0;
    s[t] = v;
    __syncthreads();
    for (int d = 1; d < SCAN_B; d <<= 1) {
        int add = (t >= d) ? s[t - d] : 0;
        __syncthreads();
        s[t] += add;
        __syncthreads();
    }
    if (i < n) rp[i] = s[t] - v;
    if (t == SCAN_B - 1) bsum[blockIdx.x] = s[t];
}

__global__ void k_scan_bsums(const int* __restrict__ bsum, int* __restrict__ boff, int nb) {
    __shared__ int s[SCAN_B];
    int t = threadIdx.x;
    int v = (t < nb) ? bsum[t] : 0;
    s[t] = v;
    __syncthreads();
    for (int d = 1; d < SCAN_B; d <<= 1) {
        int add = (t >= d) ? s[t - d] : 0;
        __syncthreads();
        s[t] += add;
        __syncthreads();
    }
    if (t < nb) boff[t] = s[t] - v;
    if (t == SCAN_B - 1) boff[nb] = s[t];
}

__global__ void k_add_off(int* __restrict__ rp, int* __restrict__ cur,
                          const int* __restrict__ boff, int n, int nb) {
    int i = blockIdx.x * SCAN_B + threadIdx.x;
    if (i < n) {
        int v = rp[i] + boff[blockIdx.x];
        rp[i] = v;
        cur[i] = v;
    }
    if (i == n) rp[n] = boff[nb];
}

__global__ void k_scatter(const int* __restrict__ erow, const int* __restrict__ ecol,
                          const float* __restrict__ eval, int* __restrict__ cur,
                          int2* __restrict__ edges, int nE) {
    int e = blockIdx.x * 256 + threadIdx.x;
    if (e >= nE) return;
    int pos = atomicAdd(&cur[erow[e]], 1);
    edges[pos] = make_int2(ecol[e], __float_as_int(eval[e]));
}

// ---------------- weight prep: bf16, B in [col][k] layout ----------------

// Wb[c][k] = bf16(W[k][c])  (W: [256][128]) ; catWb = bf16(catW) (already [col][k])
__global__ void k_prep(const float* __restrict__ W, const float* __restrict__ catW,
                       u16* __restrict__ Wb, u16* __restrict__ catWb) {
    int idx = blockIdx.x * 256 + threadIdx.x;
    if (idx < F_IN * EDIM) {
        int k = idx >> 7;         // 0..255
        int c = idx & 127;        // 0..127
        Wb[c * F_IN + k] = f2b(W[idx]);
    } else {
        int j = idx - F_IN * EDIM;
        if (j < EDIM * 2 * EDIM) catWb[j] = f2b(catW[j]);
    }
}

// ---------------- MFMA GEMMs ----------------
// Tile: 128 rows x 128 cols, 4 waves (2x2), per-wave 64x64 = 4x4 frags of
// 16x16, K-step 32 via mfma_f32_16x16x32_bf16.
// LDS: As[row][k] bf16 (stride 40), Bs[col][k] bf16 (stride 40).
// Frag: lane&15 -> row/col, lane>>4 -> k-group of 8; C/D: col=lane&15,
// row=(lane>>4)*4+reg (verified layout).

#define LSTRIDE 40

// support(bf16) = relu(feature @ W)
__global__ __launch_bounds__(256) void k_gemm1_relu(const float* __restrict__ feature,
                                                    const u16* __restrict__ Wb,
                                                    u16* __restrict__ supb, int n) {
    __shared__ __align__(16) u16 As[BM][LSTRIDE];
    __shared__ __align__(16) u16 Bs[EDIM][LSTRIDE];
    const int t = threadIdx.x;
    const int r0 = blockIdx.x * BM;
    const int w = t >> 6, lane = t & 63;
    const int wr = w >> 1, wc = w & 1;
    const int lm = lane & 15, kg = lane >> 4;

    f32x4 acc[4][4];
    #pragma unroll
    for (int m = 0; m < 4; ++m)
        #pragma unroll
        for (int nn = 0; nn < 4; ++nn)
            acc[m][nn] = (f32x4){0.f, 0.f, 0.f, 0.f};

    const int srow = t >> 1;            // staging row/col
    const int koff = (t & 1) * 16;

    for (int kt = 0; kt < F_IN / 32; ++kt) {
        const int k0 = kt * 32;
        // ---- stage A: feature f32 -> bf16 ----
        {
            u32 pk[8];
            if (r0 + srow < n) {
                const float* src = feature + (size_t)(r0 + srow) * F_IN + k0 + koff;
                #pragma unroll
                for (int q = 0; q < 4; ++q) {
                    float4 f = *reinterpret_cast<const float4*>(src + q * 4);
                    pk[q * 2 + 0] = pack2(f.x, f.y);
                    pk[q * 2 + 1] = pack2(f.z, f.w);
                }
            } else {
                #pragma unroll
                for (int q = 0; q < 8; ++q) pk[q] = 0;
            }
            uint4* dst = reinterpret_cast<uint4*>(&As[srow][koff]);
            dst[0] = make_uint4(pk[0], pk[1], pk[2], pk[3]);
            dst[1] = make_uint4(pk[4], pk[5], pk[6], pk[7]);
        }
        // ---- stage B: Wb [col][k] bf16 copy ----
        {
            const uint4* src = reinterpret_cast<const uint4*>(Wb + (size_t)srow * F_IN + k0 + koff);
            uint4* dst = reinterpret_cast<uint4*>(&Bs[srow][koff]);
            dst[0] = src[0];
            dst[1] = src[1];
        }
        __syncthreads();
        #pragma unroll
        for (int m = 0; m < 4; ++m) {
            bf16x8 a = *reinterpret_cast<const bf16x8*>(&As[wr * 64 + m * 16 + lm][kg * 8]);
            #pragma unroll
            for (int nn = 0; nn < 4; ++nn) {
                bf16x8 b = *reinterpret_cast<const bf16x8*>(&Bs[wc * 64 + nn * 16 + lm][kg * 8]);
                acc[m][nn] = __builtin_amdgcn_mfma_f32_16x16x32_bf16(a, b, acc[m][nn], 0, 0, 0);
            }
        }
        __syncthreads();
    }
    // ---- epilogue: relu -> bf16 ----
    #pragma unroll
    for (int m = 0; m < 4; ++m) {
        #pragma unroll
        for (int r = 0; r < 4; ++r) {
            int row = r0 + wr * 64 + m * 16 + kg * 4 + r;
            if (row >= n) continue;
            u16* dst = supb + (size_t)row * EDIM;
            #pragma unroll
            for (int nn = 0; nn < 4; ++nn) {
                int col = wc * 64 + nn * 16 + lm;
                dst[col] = f2b(fmaxf(acc[m][nn][r], 0.f));
            }
        }
    }
}

// out = leaky_relu([s1+sup | s2-sup] @ catW^T + catb) + b
__global__ __launch_bounds__(256) void k_final(const u16* __restrict__ supb,
                                               const u16* __restrict__ s1b,
                                               const u16* __restrict__ s2b,
                                               float* __restrict__ out,
                                               const u16* __restrict__ catWb,
                                               const float* __restrict__ catb,
                                               const float* __restrict__ bvec, int n) {
    __shared__ __align__(16) u16 As[BM][LSTRIDE];
    __shared__ __align__(16) u16 Bs[EDIM][LSTRIDE];
    const int t = threadIdx.x;
    const int r0 = blockIdx.x * BM;
    const int w = t >> 6, lane = t & 63;
    const int wr = w >> 1, wc = w & 1;
    const int lm = lane & 15, kg = lane >> 4;

    f32x4 acc[4][4];
    #pragma unroll
    for (int m = 0; m < 4; ++m)
        #pragma unroll
        for (int nn = 0; nn < 4; ++nn)
            acc[m][nn] = (f32x4){0.f, 0.f, 0.f, 0.f};

    const int srow = t >> 1;
    const int koff = (t & 1) * 16;

    for (int kt = 0; kt < (2 * EDIM) / 32; ++kt) {
        const int k0 = kt * 32;
        // ---- stage A: cat tile on the fly (bf16 in, f32 add, bf16 out) ----
        {
            u32 pk[8];
            if (r0 + srow < n) {
                const int kk = k0 + koff;                 // whole 16-chunk in one half
                const int lo = (kk < EDIM);
                const int kcol = lo ? kk : kk - EDIM;
                size_t off = (size_t)(r0 + srow) * EDIM + kcol;
                const uint4* pa = reinterpret_cast<const uint4*>((lo ? s1b : s2b) + off);
                const uint4* pq = reinterpret_cast<const uint4*>(supb + off);
                uint4 a0 = pa[0], a1 = pa[1];
                uint4 q0 = pq[0], q1 = pq[1];
                const u32 av[8] = {a0.x, a0.y, a0.z, a0.w, a1.x, a1.y, a1.z, a1.w};
                const u32 qv[8] = {q0.x, q0.y, q0.z, q0.w, q1.x, q1.y, q1.z, q1.w};
                const float sgn = lo ? 1.f : -1.f;
                #pragma unroll
                for (int q = 0; q < 8; ++q) {
                    float x = unpack_lo(av[q]) + sgn * unpack_lo(qv[q]);
                    float y = unpack_hi(av[q]) + sgn * unpack_hi(qv[q]);
                    pk[q] = pack2(x, y);
                }
            } else {
                #pragma unroll
                for (int q = 0; q < 8; ++q) pk[q] = 0;
            }
            uint4* dst = reinterpret_cast<uint4*>(&As[srow][koff]);
            dst[0] = make_uint4(pk[0], pk[1], pk[2], pk[3]);
            dst[1] = make_uint4(pk[4], pk[5], pk[6], pk[7]);
        }
        // ---- stage B: catWb [col][k] copy ----
        {
            const uint4* src = reinterpret_cast<const uint4*>(catWb + (size_t)srow * (2 * EDIM) + k0 + koff);
            uint4* dst = reinterpret_cast<uint4*>(&Bs[srow][koff]);
            dst[0] = src[0];
            dst[1] = src[1];
        }
        __syncthreads();
        #pragma unroll
        for (int m = 0; m < 4; ++m) {
            bf16x8 a = *reinterpret_cast<const bf16x8*>(&As[wr * 64 + m * 16 + lm][kg * 8]);
            #pragma unroll
            for (int nn = 0; nn < 4; ++nn) {
                bf16x8 b = *reinterpret_cast<const bf16x8*>(&Bs[wc * 64 + nn * 16 + lm][kg * 8]);
                acc[m][nn] = __builtin_amdgcn_mfma_f32_16x16x32_bf16(a, b, acc[m][nn], 0, 0, 0);
            }
        }
        __syncthreads();
    }
    // ---- epilogue: +catb, leaky, +b, f32 out ----
    #pragma unroll
    for (int nn = 0; nn < 4; ++nn) {
        int col = wc * 64 + nn * 16 + lm;
        float cbv = catb[col];
        float bbv = bvec[col];
        #pragma unroll
        for (int m = 0; m < 4; ++m) {
            #pragma unroll
            for (int r = 0; r < 4; ++r) {
                int row = r0 + wr * 64 + m * 16 + kg * 4 + r;
                if (row >= n) continue;
                float v = acc[m][nn][r] + cbv;
                v = (v > 0.f ? v : ALPHA * v) + bbv;
                out[(size_t)row * EDIM + col] = v;
            }
        }
    }
}

// y(bf16) = A @ x(bf16): one wave per dest row, lane = 2 cols, f32 accum.
__global__ void k_spmm_csr(const int* __restrict__ rowptr, const int2* __restrict__ edges,
                           const u16* __restrict__ xb, u16* __restrict__ yb, int n) {
    int wid = threadIdx.x >> 6;
    int lane = threadIdx.x & 63;
    int row = blockIdx.x * 4 + wid;
    if (row >= n) return;
    int beg = rowptr[row];
    int end = rowptr[row + 1];
    int c = lane * 2;
    float ax = 0.f, ay = 0.f;
    int j = beg;
    for (; j + 4 <= end; j += 4) {
        int2 e0 = edges[j];
        int2 e1 = edges[j + 1];
        int2 e2 = edges[j + 2];
        int2 e3 = edges[j + 3];
        u32 g0 = *reinterpret_cast<const u32*>(xb + (size_t)e0.x * EDIM + c);
        u32 g1 = *reinterpret_cast<const u32*>(xb + (size_t)e1.x * EDIM + c);
        u32 g2 = *reinterpret_cast<const u32*>(xb + (size_t)e2.x * EDIM + c);
        u32 g3 = *reinterpret_cast<const u32*>(xb + (size_t)e3.x * EDIM + c);
        float v0 = __int_as_float(e0.y), v1 = __int_as_float(e1.y);
        float v2 = __int_as_float(e2.y), v3 = __int_as_float(e3.y);
        ax = fmaf(v0, unpack_lo(g0), ax); ay = fmaf(v0, unpack_hi(g0), ay);
        ax = fmaf(v1, unpack_lo(g1), ax); ay = fmaf(v1, unpack_hi(g1), ay);
        ax = fmaf(v2, unpack_lo(g2), ax); ay = fmaf(v2, unpack_hi(g2), ay);
        ax = fmaf(v3, unpack_lo(g3), ax); ay = fmaf(v3, unpack_hi(g3), ay);
    }
    for (; j < end; ++j) {
        int2 e = edges[j];
        u32 g = *reinterpret_cast<const u32*>(xb + (size_t)e.x * EDIM + c);
        float v = __int_as_float(e.y);
        ax = fmaf(v, unpack_lo(g), ax);
        ay = fmaf(v, unpack_hi(g), ay);
    }
    *reinterpret_cast<u32*>(yb + (size_t)row * EDIM + c) = pack2(ax, ay);
}

extern "C" void kernel_launch(void* const* d_in, const int* in_sizes, int n_in,
                              void* d_out, int out_size, void* d_ws, size_t ws_size,
                              hipStream_t stream) {
    const float* feature = (const float*)d_in[0];
    const int*   erow    = (const int*)d_in[1];
    const int*   ecol    = (const int*)d_in[2];
    const float* eval    = (const float*)d_in[3];
    const float* W       = (const float*)d_in[4];
    const float* b       = (const float*)d_in[5];
    const float* catW    = (const float*)d_in[6];
    const float* catb    = (const float*)d_in[7];
    float* out = (float*)d_out;

    const int n  = in_sizes[0] / F_IN;
    const int nE = in_sizes[1];
    const int nb = (n + SCAN_B - 1) / SCAN_B;

    char* p = (char*)d_ws;
    u16*  supb = (u16*)p;                   p += (size_t)n * EDIM * sizeof(u16);
    u16*  s1b  = (u16*)p;                   p += (size_t)n * EDIM * sizeof(u16);
    u16*  s2b  = (u16*)p;                   p += (size_t)n * EDIM * sizeof(u16);
    p = (char*)(((size_t)p + 15) & ~(size_t)15);
    u16*  Wb   = (u16*)p;                   p += (size_t)F_IN * EDIM * sizeof(u16);
    u16*  catWb = (u16*)p;                  p += (size_t)EDIM * 2 * EDIM * sizeof(u16);
    p = (char*)(((size_t)p + 15) & ~(size_t)15);
    int2* edges = (int2*)p;                 p += (size_t)nE * sizeof(int2);
    int*  cnt   = (int*)p;                  p += (size_t)n * sizeof(int);
    int*  rowptr = (int*)p;                 p += (size_t)(n + 1) * sizeof(int);
    int*  cur    = (int*)p;                 p += (size_t)n * sizeof(int);
    int*  bsum   = (int*)p;                 p += (size_t)nb * sizeof(int);
    int*  boff   = (int*)p;                 p += (size_t)(nb + 1) * sizeof(int);

    const int eB = (nE + 255) / 256;
    const int gemmBlocks = (n + BM - 1) / BM;
    const int spmmBlocks = (n + 3) / 4;

    // ---- CSR build (row-level counting sort; round-4 proven variant) ----
    hipMemsetAsync(cnt, 0, (size_t)n * sizeof(int), stream);
    k_hist<<<eB, 256, 0, stream>>>(erow, cnt, nE);
    k_scan_block<<<nb, SCAN_B, 0, stream>>>(cnt, rowptr, bsum, n);
    k_scan_bsums<<<1, SCAN_B, 0, stream>>>(bsum, boff, nb);
    k_add_off<<<nb, SCAN_B, 0, stream>>>(rowptr, cur, boff, n, nb);
    k_scatter<<<eB, 256, 0, stream>>>(erow, ecol, eval, cur, edges, nE);

    // ---- weight prep + GEMM1 ----
    k_prep<<<(F_IN * EDIM + EDIM * 2 * EDIM + 255) / 256, 256, 0, stream>>>(W, catW, Wb, catWb);
    k_gemm1_relu<<<gemmBlocks, 256, 0, stream>>>(feature, Wb, supb, n);

    // ---- SpMMs (bf16 gather, f32 accum) ----
    k_spmm_csr<<<spmmBlocks, 256, 0, stream>>>(rowptr, edges, supb, s1b, n);
    k_spmm_csr<<<spmmBlocks, 256, 0, stream>>>(rowptr, edges, s1b, s2b, n);

    // ---- epilogue GEMM ----
    k_final<<<gemmBlocks, 256, 0, stream>>>(supb, s1b, s2b, out, catWb, catb, b, n);
}